// Round 7
// baseline (1081.534 us; speedup 1.0000x reference)
//
#include <hip/hip_runtime.h>
#include <stdint.h>

// QLoRA BigNet forward, MI355X/gfx950.  R7.
// gemm5: faithful m201 8-phase port with corrected flight-depth ledger.
// BM=BN=256, BK=64, 16 K-tiles, 8 waves (2Mx4N), LDS 128KB:
// A slots @0/32768 (even/odd tiles), B slots @65536/98304.
// Phase = {[q0: 24 ds_reads] | 1 half-tile stage | [ph4/ph8: vmcnt(4)] |
//          BAR | setprio(1) 16-MFMA quadrant setprio(0) | BAR}.
// Stage order per iter (tiles u,u+1): A(u+1)@ph1-2, B(u+2)@ph3-4,
// A(u+2)@ph5-6, B(u+3)@ph7-8.  vmcnt(4)@ph4 retires B(u+1)[5-phase flight]
// +A(u+1); vmcnt(4)@ph8 retires B(u+2)+A(u+2). Never drains mid-loop.
// WAR audit: B(v) LDS freed after ph(v,q0) MFMA-wait + barrier -> B(v+2)
// staged >=2 phases later; A(v) freed after ph(v,q3) -> A(v+2) next phase.

#define TOK   16384
#define DIM   1024
#define NLIN  18
#define EPS   1e-5f

typedef _Float16 f16;
typedef _Float16 f16x8 __attribute__((ext_vector_type(8)));
typedef _Float16 f16x4 __attribute__((ext_vector_type(4)));
typedef float    f32x4 __attribute__((ext_vector_type(4)));

__device__ __forceinline__ void load_lds16(const void* g, void* l) {
  __builtin_amdgcn_global_load_lds(
      (const __attribute__((address_space(1))) void*)g,
      (__attribute__((address_space(3))) void*)l,
      16, 0, 0);
}

// ---------------------------------------------------------------------------
// prep v2 (validated R4)
// ---------------------------------------------------------------------------
__global__ __launch_bounds__(256) void prep_w2(
    const int* __restrict__ q, const float* __restrict__ norm,
    const float* __restrict__ la, const float* __restrict__ lb,
    f16* __restrict__ W)
{
  __shared__ float lbs[128 * 32];
  const int bid   = blockIdx.x;
  const int i     = bid >> 5;
  const int ot    = (bid >> 2) & 7;
  const int ktile = bid & 3;
  const int o0 = ot * 128, k0 = ktile * 256;
  const int tid = threadIdx.x;
  const int kg = tid & 63, og = tid >> 6;
  const int k4 = k0 + kg * 4;

  const float* lbsrc = lb + (size_t)i * DIM * 32 + (size_t)o0 * 32;
  #pragma unroll
  for (int p = 0; p < 4; ++p)
    *(float4*)(lbs + p * 1024 + tid * 4) = *(const float4*)(lbsrc + p * 1024 + tid * 4);

  float4 lar[32];
  const float* lasrc = la + (size_t)i * 32 * DIM + k4;
  #pragma unroll
  for (int r = 0; r < 32; ++r) lar[r] = *(const float4*)(lasrc + r * DIM);
  __syncthreads();

  const float s = 2.f / 15.f;
  for (int oi = 0; oi < 32; ++oi) {
    const int o = o0 + og * 32 + oi;
    const size_t wb = ((size_t)i * DIM + o) * DIM;
    const int4 qv = *(const int4*)(q + wb + k4);
    const float nrm = norm[((size_t)i * DIM + o) * 8 + (k4 >> 7)];
    const float* lbr = lbs + (og * 32 + oi) * 32;
    float ax = 0.f, ay = 0.f, az = 0.f, aw = 0.f;
    #pragma unroll
    for (int r = 0; r < 32; ++r) {
      const float b = lbr[r];
      ax += b * lar[r].x; ay += b * lar[r].y; az += b * lar[r].z; aw += b * lar[r].w;
    }
    f16x4 hv;
    hv[0] = (f16)(((float)qv.x * s - 1.f) * nrm + ax);
    hv[1] = (f16)(((float)qv.y * s - 1.f) * nrm + ay);
    hv[2] = (f16)(((float)qv.z * s - 1.f) * nrm + az);
    hv[3] = (f16)(((float)qv.w * s - 1.f) * nrm + aw);
    *(f16x4*)(W + wb + k4) = hv;
  }
}

// ---------------------------------------------------------------------------
__global__ __launch_bounds__(256) void cvt_x(
    const float* __restrict__ x, f16* __restrict__ o)
{
  const size_t idx = ((size_t)blockIdx.x * 256 + threadIdx.x) * 4;
  const float4 v = *(const float4*)(x + idx);
  f16x4 h;
  h[0] = (f16)v.x; h[1] = (f16)v.y; h[2] = (f16)v.z; h[3] = (f16)v.w;
  *(f16x4*)(o + idx) = h;
}

// ---------------------------------------------------------------------------
// gemm5.  EPI 0: relu->f16  1: +resid->f16  2: +resid->f32
// ---------------------------------------------------------------------------
#define BARX() __builtin_amdgcn_s_barrier()
#define SA0 0
#define SA1 32768
#define SB0 65536
#define SB1 98304

#define LDA(sa, mi, kk) (*(const f16x8*)(smem + (sa) + wmbase + arowb[mi] + (ckA ^ ((kk) << 6))))
#define LDB(sb, ni, kk) (*(const f16x8*)(smem + (sb) + wnhalf + browb[ni] + (ckA ^ ((kk) << 6))))

// all 24 ds_read_b128 for one K-tile; q0 fragments + all bf issued first
#define RD_ALL(sa, sb) do { \
  af[0][0] = LDA(sa, 0, 0); af[0][1] = LDA(sa, 0, 1); \
  af[1][0] = LDA(sa, 1, 0); af[1][1] = LDA(sa, 1, 1); \
  bf[0][0] = LDB(sb, 0, 0); bf[0][1] = LDB(sb, 0, 1); \
  bf[1][0] = LDB(sb, 1, 0); bf[1][1] = LDB(sb, 1, 1); \
  bf[2][0] = LDB(sb, 2, 0); bf[2][1] = LDB(sb, 2, 1); \
  bf[3][0] = LDB(sb, 3, 0); bf[3][1] = LDB(sb, 3, 1); \
  af[2][0] = LDA(sa, 2, 0); af[2][1] = LDA(sa, 2, 1); \
  af[3][0] = LDA(sa, 3, 0); af[3][1] = LDA(sa, 3, 1); \
  af[4][0] = LDA(sa, 4, 0); af[4][1] = LDA(sa, 4, 1); \
  af[5][0] = LDA(sa, 5, 0); af[5][1] = LDA(sa, 5, 1); \
  af[6][0] = LDA(sa, 6, 0); af[6][1] = LDA(sa, 6, 1); \
  af[7][0] = LDA(sa, 7, 0); af[7][1] = LDA(sa, 7, 1); \
} while (0)

// one C-quadrant (rows 2q,2q+1 of frag grid) x full K=64: 16 MFMAs
#define QUADQ(q) do { \
  __builtin_amdgcn_s_setprio(1); \
  _Pragma("unroll") \
  for (int ni = 0; ni < 4; ++ni) { \
    acc[2*(q)][ni]   = __builtin_amdgcn_mfma_f32_16x16x32_f16(af[2*(q)][0],   bf[ni][0], acc[2*(q)][ni],   0, 0, 0); \
    acc[2*(q)][ni]   = __builtin_amdgcn_mfma_f32_16x16x32_f16(af[2*(q)][1],   bf[ni][1], acc[2*(q)][ni],   0, 0, 0); \
    acc[2*(q)+1][ni] = __builtin_amdgcn_mfma_f32_16x16x32_f16(af[2*(q)+1][0], bf[ni][0], acc[2*(q)+1][ni], 0, 0, 0); \
    acc[2*(q)+1][ni] = __builtin_amdgcn_mfma_f32_16x16x32_f16(af[2*(q)+1][1], bf[ni][1], acc[2*(q)+1][ni], 0, 0, 0); \
  } \
  __builtin_amdgcn_s_setprio(0); \
} while (0)

// stage one half (128 rows) of an operand K-tile: 2 x global_load_lds (8KB ea)
#define STAGE_A(T, h, base) do { \
  load_lds16(gA + (size_t)((T) * 64) + (size_t)((h) * 128) * DIM, \
             smem + (base) + (h) * 16384 + sdst); \
  load_lds16(gA + (size_t)((T) * 64) + (size_t)((h) * 128 + 64) * DIM, \
             smem + (base) + (h) * 16384 + 8192 + sdst); \
} while (0)
#define STAGE_B(T, h, base) do { \
  load_lds16(gB + (size_t)((T) * 64) + (size_t)((h) * 128) * DIM, \
             smem + (base) + (h) * 16384 + sdst); \
  load_lds16(gB + (size_t)((T) * 64) + (size_t)((h) * 128 + 64) * DIM, \
             smem + (base) + (h) * 16384 + 8192 + sdst); \
} while (0)

#define VMC(n) asm volatile("s_waitcnt vmcnt(" #n ")" ::: "memory")

template<int EPI>
__global__ __launch_bounds__(512, 2) void gemm5(
    const f16* __restrict__ A, const f16* __restrict__ W,
    const float* __restrict__ bias, const f16* __restrict__ resid,
    void* __restrict__ outp)
{
  __shared__ __align__(16) char smem[131072];

  // XCD swizzle: 256 blocks, 8 XCDs -> 32 consecutive per XCD (8 mt x 4 nt).
  const int orig = blockIdx.x;
  const int swzb = (orig & 7) * 32 + (orig >> 3);
  const int mt = swzb >> 2, nt = swzb & 3;
  const int t0 = mt * 256, n0 = nt * 256;

  const int tid  = threadIdx.x;
  const int lane = tid & 63;
  const int wid  = tid >> 6;
  const int wm = wid >> 2, wn = wid & 3;          // 2M x 4N waves

  // staging addressing (global source pre-swizzled: chunk ^= row&7)
  const int srow = tid >> 3;                      // 0..63
  const int sch  = (tid & 7) ^ (srow & 7);
  const f16* gA = A + (size_t)(t0 + srow) * DIM + sch * 8;
  const f16* gB = W + (size_t)(n0 + srow) * DIM + sch * 8;
  const int sdst = tid * 16;

  // fragment addressing (row bases 16-aligned -> row&7 == lane&7)
  const int ckA    = (((lane >> 4) ^ (lane & 7)) << 4);
  const int wmbase = wm * 16384;
  const int wnhalf = (wn >> 1) * 16384;
  int arowb[8], browb[4];
  #pragma unroll
  for (int mi = 0; mi < 8; ++mi)
    arowb[mi] = (mi * 16 + (lane & 15)) * 128;
  #pragma unroll
  for (int ni = 0; ni < 4; ++ni)
    browb[ni] = ((wn & 1) * 64 + ni * 16 + (lane & 15)) * 128;

  f32x4 acc[8][4] = {};
  f16x8 af[8][2], bf[4][2];

  // prologue: A(0),B(0) -> even slots; B(1) -> odd B slot.  FIFO: A0,B0,B1.
  STAGE_A(0, 0, SA0); STAGE_A(0, 1, SA0);
  STAGE_B(0, 0, SB0); STAGE_B(0, 1, SB0);
  STAGE_B(1, 0, SB1); STAGE_B(1, 1, SB1);
  VMC(4);                      // A(0),B(0) landed; B(1) in flight
  BARX();

  for (int it = 0; it < 8; ++it) {
    const int u = it * 2;
    // ph1 (u,q0): all reads tile u | stage Ah0(u+1)
    RD_ALL(SA0, SB0);
    if (u + 1 < 16) STAGE_A(u + 1, 0, SA1);
    BARX(); QUADQ(0); BARX();
    // ph2: stage Ah1(u+1)
    if (u + 1 < 16) STAGE_A(u + 1, 1, SA1);
    BARX(); QUADQ(1); BARX();
    // ph3: stage Bh0(u+2)  [B(u) LDS freed at ph1 MFMA-wait + barriers]
    if (u + 2 < 16) STAGE_B(u + 2, 0, SB0);
    BARX(); QUADQ(2); BARX();
    // ph4: stage Bh1(u+2) | vmcnt: retire B(u+1)[5-ph flight] + A(u+1)
    if (u + 2 < 16) { STAGE_B(u + 2, 1, SB0); VMC(4); }
    else            { VMC(0); }
    BARX(); QUADQ(3); BARX();
    // ph5 (u+1,q0): all reads tile u+1 | stage Ah0(u+2) [A(u) freed ph4]
    RD_ALL(SA1, SB1);
    if (u + 2 < 16) STAGE_A(u + 2, 0, SA0);
    BARX(); QUADQ(0); BARX();
    // ph6: stage Ah1(u+2)
    if (u + 2 < 16) STAGE_A(u + 2, 1, SA0);
    BARX(); QUADQ(1); BARX();
    // ph7: stage Bh0(u+3)  [B(u+1) freed at ph5]
    if (u + 3 < 16) STAGE_B(u + 3, 0, SB1);
    BARX(); QUADQ(2); BARX();
    // ph8: stage Bh1(u+3) | vmcnt: retire B(u+2)+A(u+2), keep B(u+3)
    if (u + 3 < 16) { STAGE_B(u + 3, 1, SB1); VMC(4); }
    BARX(); QUADQ(3); BARX();
  }

  // epilogue: C/D col=lane&15, row=(lane>>4)*4+r
  const int colb = lane & 15;
  const int rowb = (lane >> 4) << 2;
  #pragma unroll
  for (int ni = 0; ni < 4; ++ni) {
    const int col = n0 + wn * 64 + ni * 16 + colb;
    const float bv = bias[col];
    #pragma unroll
    for (int mi = 0; mi < 8; ++mi) {
      const int trow = t0 + wm * 128 + mi * 16 + rowb;
      const f32x4 v = acc[mi][ni];
      #pragma unroll
      for (int r = 0; r < 4; ++r) {
        const size_t idx = (size_t)(trow + r) * DIM + col;
        float val = v[r] + bv;
        if constexpr (EPI == 0) {
          val = fmaxf(val, 0.f);
          ((f16*)outp)[idx] = (f16)val;
        } else if constexpr (EPI == 1) {
          val += (float)resid[idx];
          ((f16*)outp)[idx] = (f16)val;
        } else {
          val += (float)resid[idx];
          ((float*)outp)[idx] = val;
        }
      }
    }
  }
}

// ---------------------------------------------------------------------------
// LayerNorm over DIM=1024, one block per row, in-place safe.
// ---------------------------------------------------------------------------
__global__ __launch_bounds__(256) void ln_k(
    const f16* __restrict__ in, f16* __restrict__ out,
    const float* __restrict__ g, const float* __restrict__ b)
{
  __shared__ float red[8];
  const int row = blockIdx.x;
  const int tid = threadIdx.x;
  const int c = tid * 4;
  const f16x4 v4 = *(const f16x4*)(in + (size_t)row * DIM + c);
  const float v0 = v4[0], v1 = v4[1], v2 = v4[2], v3 = v4[3];
  float s  = v0 + v1 + v2 + v3;
  float s2 = v0 * v0 + v1 * v1 + v2 * v2 + v3 * v3;
  #pragma unroll
  for (int off = 32; off; off >>= 1) {
    s  += __shfl_xor(s,  off);
    s2 += __shfl_xor(s2, off);
  }
  if ((tid & 63) == 0) { red[(tid >> 6) * 2] = s; red[(tid >> 6) * 2 + 1] = s2; }
  __syncthreads();
  s  = red[0] + red[2] + red[4] + red[6];
  s2 = red[1] + red[3] + red[5] + red[7];
  const float mu  = s * (1.f / DIM);
  const float var = fmaxf(s2 * (1.f / DIM) - mu * mu, 0.f);
  const float rs  = rsqrtf(var + EPS);
  const float4 gv = *(const float4*)(g + c);
  const float4 bv = *(const float4*)(b + c);
  f16x4 o4;
  o4[0] = (f16)((v0 - mu) * rs * gv.x + bv.x);
  o4[1] = (f16)((v1 - mu) * rs * gv.y + bv.y);
  o4[2] = (f16)((v2 - mu) * rs * gv.z + bv.z);
  o4[3] = (f16)((v3 - mu) * rs * gv.w + bv.w);
  *(f16x4*)(out + (size_t)row * DIM + c) = o4;
}

// ---------------------------------------------------------------------------
extern "C" void kernel_launch(void* const* d_in, const int* in_sizes, int n_in,
                              void* d_out, int out_size, void* d_ws, size_t ws_size,
                              hipStream_t stream)
{
  (void)in_sizes; (void)n_in; (void)out_size; (void)ws_size;
  const float* x     = (const float*)d_in[0];
  const int*   q     = (const int*)d_in[1];
  const float* norm  = (const float*)d_in[2];
  const float* bias  = (const float*)d_in[3];
  const float* la    = (const float*)d_in[4];
  const float* lb    = (const float*)d_in[5];
  const float* lg    = (const float*)d_in[6];
  const float* lbeta = (const float*)d_in[7];

  char* ws = (char*)d_ws;
  f16* W    = (f16*)ws;                                   // 36 MB
  f16* buf1 = (f16*)(ws + (size_t)NLIN * DIM * DIM * 2);  // 32 MB
  f16* buf2 = buf1 + (size_t)TOK * DIM;                   // 32 MB
  f16* buf0 = (f16*)d_out;  // scratch inside the 64MB output; dead at final GEMM
  f16* bufs[3] = {buf0, buf1, buf2};

  prep_w2<<<NLIN * 32, 256, 0, stream>>>(q, norm, la, lb, W);
  cvt_x<<<TOK * DIM / 1024, 256, 0, stream>>>(x, buf0);

  int h = 0;
  for (int blk = 0; blk < 6; ++blk) {
    const int a = (h == 0) ? 1 : 0;
    const int p = 3 - h - a;
    const int i0 = blk * 3;
    const size_t wsz = (size_t)DIM * DIM;
    gemm5<0><<<256, 512, 0, stream>>>(bufs[h], W + (i0 + 0) * wsz,
                                      bias + (i0 + 0) * DIM, nullptr, bufs[a]);
    gemm5<0><<<256, 512, 0, stream>>>(bufs[a], W + (i0 + 1) * wsz,
                                      bias + (i0 + 1) * DIM, nullptr, bufs[p]);
    if (blk < 5) {
      gemm5<1><<<256, 512, 0, stream>>>(bufs[p], W + (i0 + 2) * wsz,
                                        bias + (i0 + 2) * DIM, bufs[h], bufs[a]);
      ln_k<<<TOK, 256, 0, stream>>>(bufs[a], bufs[a], lg + blk * DIM, lbeta + blk * DIM);
      h = a;
    } else {
      gemm5<2><<<256, 512, 0, stream>>>(bufs[p], W + (i0 + 2) * wsz,
                                        bias + (i0 + 2) * DIM, bufs[h], d_out);
    }
  }
}

// Round 8
// 967.496 us; speedup vs baseline: 1.1179x; 1.1179x over previous
//
#include <hip/hip_runtime.h>
#include <stdint.h>

// QLoRA BigNet forward, MI355X/gfx950.  R8.
// gemm6: occupancy-first. 128x128 tile, BK=64, 4 waves, LDS 64KB (2 slots) ->
// 2 INDEPENDENT blocks/CU (separate barrier groups give MFMA<->stage overlap
// that intra-block phase scheduling failed to deliver in R4-R7: 5 schedule
// variants all ~600TF/MfmaUtil 22% at 1 block/CU lockstep).
// Pipeline per iter t: VMC(8)[own-wave slice of tile t] -> BAR -> ds_read
// slot(t&1) -> BAR -> stage tile t+2 into slot(t&1) [~2-tile flight] ->
// sched_barrier -> 32 MFMA (setprio).  vmcnt never drains until t=15.
// Swizzle: chunk ^= row&7 on 128B rows, both-sides (verified R4-R7, 0 conflicts).

#define TOK   16384
#define DIM   1024
#define NLIN  18
#define EPS   1e-5f

typedef _Float16 f16;
typedef _Float16 f16x8 __attribute__((ext_vector_type(8)));
typedef _Float16 f16x4 __attribute__((ext_vector_type(4)));
typedef float    f32x4 __attribute__((ext_vector_type(4)));

__device__ __forceinline__ void load_lds16(const void* g, void* l) {
  __builtin_amdgcn_global_load_lds(
      (const __attribute__((address_space(1))) void*)g,
      (__attribute__((address_space(3))) void*)l,
      16, 0, 0);
}

// ---------------------------------------------------------------------------
// prep v2 (validated R4)
// ---------------------------------------------------------------------------
__global__ __launch_bounds__(256) void prep_w2(
    const int* __restrict__ q, const float* __restrict__ norm,
    const float* __restrict__ la, const float* __restrict__ lb,
    f16* __restrict__ W)
{
  __shared__ float lbs[128 * 32];
  const int bid   = blockIdx.x;
  const int i     = bid >> 5;
  const int ot    = (bid >> 2) & 7;
  const int ktile = bid & 3;
  const int o0 = ot * 128, k0 = ktile * 256;
  const int tid = threadIdx.x;
  const int kg = tid & 63, og = tid >> 6;
  const int k4 = k0 + kg * 4;

  const float* lbsrc = lb + (size_t)i * DIM * 32 + (size_t)o0 * 32;
  #pragma unroll
  for (int p = 0; p < 4; ++p)
    *(float4*)(lbs + p * 1024 + tid * 4) = *(const float4*)(lbsrc + p * 1024 + tid * 4);

  float4 lar[32];
  const float* lasrc = la + (size_t)i * 32 * DIM + k4;
  #pragma unroll
  for (int r = 0; r < 32; ++r) lar[r] = *(const float4*)(lasrc + r * DIM);
  __syncthreads();

  const float s = 2.f / 15.f;
  for (int oi = 0; oi < 32; ++oi) {
    const int o = o0 + og * 32 + oi;
    const size_t wb = ((size_t)i * DIM + o) * DIM;
    const int4 qv = *(const int4*)(q + wb + k4);
    const float nrm = norm[((size_t)i * DIM + o) * 8 + (k4 >> 7)];
    const float* lbr = lbs + (og * 32 + oi) * 32;
    float ax = 0.f, ay = 0.f, az = 0.f, aw = 0.f;
    #pragma unroll
    for (int r = 0; r < 32; ++r) {
      const float b = lbr[r];
      ax += b * lar[r].x; ay += b * lar[r].y; az += b * lar[r].z; aw += b * lar[r].w;
    }
    f16x4 hv;
    hv[0] = (f16)(((float)qv.x * s - 1.f) * nrm + ax);
    hv[1] = (f16)(((float)qv.y * s - 1.f) * nrm + ay);
    hv[2] = (f16)(((float)qv.z * s - 1.f) * nrm + az);
    hv[3] = (f16)(((float)qv.w * s - 1.f) * nrm + aw);
    *(f16x4*)(W + wb + k4) = hv;
  }
}

// ---------------------------------------------------------------------------
__global__ __launch_bounds__(256) void cvt_x(
    const float* __restrict__ x, f16* __restrict__ o)
{
  const size_t idx = ((size_t)blockIdx.x * 256 + threadIdx.x) * 4;
  const float4 v = *(const float4*)(x + idx);
  f16x4 h;
  h[0] = (f16)v.x; h[1] = (f16)v.y; h[2] = (f16)v.z; h[3] = (f16)v.w;
  *(f16x4*)(o + idx) = h;
}

// ---------------------------------------------------------------------------
// gemm6.  EPI 0: relu->f16  1: +resid->f16  2: +resid->f32
// LDS: slot s @ s*32768: [A 16KB][B 16KB].  Tile t -> slot t&1.
// ---------------------------------------------------------------------------
#define BARX() __builtin_amdgcn_s_barrier()

#define LDA6(sb, mi, kk) (*(const f16x8*)(smem + (sb) + arowb[mi] + (ckA ^ ((kk) << 6))))
#define LDB6(sb, ni, kk) (*(const f16x8*)(smem + (sb) + 16384 + browb[ni] + (ckA ^ ((kk) << 6))))

// stage full tile T (A 16KB + B 16KB, 8 gloads; per wave: 8 vmcnt events)
#define STAGE_T(T, base) do { \
  _Pragma("unroll") \
  for (int g = 0; g < 4; ++g) \
    load_lds16(gA + (size_t)((T) * 64) + (size_t)(g * 32) * DIM, \
               smem + (base) + g * 4096 + sdst); \
  _Pragma("unroll") \
  for (int g = 0; g < 4; ++g) \
    load_lds16(gB + (size_t)((T) * 64) + (size_t)(g * 32) * DIM, \
               smem + (base) + 16384 + g * 4096 + sdst); \
} while (0)

template<int EPI>
__global__ __launch_bounds__(256, 2) void gemm6(
    const f16* __restrict__ A, const f16* __restrict__ W,
    const float* __restrict__ bias, const f16* __restrict__ resid,
    void* __restrict__ outp)
{
  __shared__ __align__(16) char smem[65536];

  // XCD swizzle: 1024 blocks, 8 XCDs -> 128 consecutive per XCD (16mt x 8nt).
  const int orig = blockIdx.x;
  const int swzb = (orig & 7) * 128 + (orig >> 3);
  const int mt = swzb >> 3, nt = swzb & 7;
  const int t0 = mt * 128, n0 = nt * 128;

  const int tid  = threadIdx.x;
  const int lane = tid & 63;
  const int wid  = tid >> 6;
  const int wm = wid >> 1, wn = wid & 1;          // 2M x 2N waves, 64x64 each

  // staging: 256 thr x 16B = 4KB = 32 rows x 8 chunks per gload.
  // LDS dest linear; global source pre-swizzled (chunk ^= row&7).
  const int srow = tid >> 3;                      // 0..31
  const int sch  = (tid & 7) ^ (srow & 7);
  const f16* gA = A + (size_t)(t0 + srow) * DIM + sch * 8;
  const f16* gB = W + (size_t)(n0 + srow) * DIM + sch * 8;
  const int sdst = tid * 16;

  // fragment addressing (row bases 16-aligned -> row&7 == lane&7)
  const int ckA = (((lane >> 4) ^ (lane & 7)) << 4);
  int arowb[4], browb[4];
  #pragma unroll
  for (int mi = 0; mi < 4; ++mi)
    arowb[mi] = (wm * 64 + mi * 16 + (lane & 15)) * 128;
  #pragma unroll
  for (int ni = 0; ni < 4; ++ni)
    browb[ni] = (wn * 64 + ni * 16 + (lane & 15)) * 128;

  f32x4 acc[4][4] = {};
  f16x8 af[4][2], bf[4][2];

  // prologue: tile0 -> slot0, tile1 -> slot1 (16 outstanding/wave)
  STAGE_T(0, 0);
  STAGE_T(1, 32768);

  for (int t = 0; t < 16; ++t) {
    const int so = (t & 1) << 15;
    // own-wave slice of tile t landed (tile t+1 stays in flight)
    if (t < 15) asm volatile("s_waitcnt vmcnt(8)" ::: "memory");
    else        asm volatile("s_waitcnt vmcnt(0)" ::: "memory");
    BARX();                                   // all waves' slices landed
    // all fragment reads for tile t
    #pragma unroll
    for (int mi = 0; mi < 4; ++mi) {
      af[mi][0] = LDA6(so, mi, 0); af[mi][1] = LDA6(so, mi, 1);
    }
    #pragma unroll
    for (int ni = 0; ni < 4; ++ni) {
      bf[ni][0] = LDB6(so, ni, 0); bf[ni][1] = LDB6(so, ni, 1);
    }
    BARX();                                   // all waves done reading slot
    if (t < 14) STAGE_T(t + 2, so);           // reuse slot; ~2-tile flight
    __builtin_amdgcn_sched_barrier(0);        // keep gloads above MFMA burst
    __builtin_amdgcn_s_setprio(1);
    #pragma unroll
    for (int mi = 0; mi < 4; ++mi)
      #pragma unroll
      for (int ni = 0; ni < 4; ++ni) {
        acc[mi][ni] = __builtin_amdgcn_mfma_f32_16x16x32_f16(
            af[mi][0], bf[ni][0], acc[mi][ni], 0, 0, 0);
        acc[mi][ni] = __builtin_amdgcn_mfma_f32_16x16x32_f16(
            af[mi][1], bf[ni][1], acc[mi][ni], 0, 0, 0);
      }
    __builtin_amdgcn_s_setprio(0);
  }

  // epilogue: C/D col=lane&15, row=(lane>>4)*4+r
  const int colb = lane & 15;
  const int rowb = (lane >> 4) << 2;
  #pragma unroll
  for (int ni = 0; ni < 4; ++ni) {
    const int col = n0 + wn * 64 + ni * 16 + colb;
    const float bv = bias[col];
    #pragma unroll
    for (int mi = 0; mi < 4; ++mi) {
      const int trow = t0 + wm * 64 + mi * 16 + rowb;
      const f32x4 v = acc[mi][ni];
      #pragma unroll
      for (int r = 0; r < 4; ++r) {
        const size_t idx = (size_t)(trow + r) * DIM + col;
        float val = v[r] + bv;
        if constexpr (EPI == 0) {
          val = fmaxf(val, 0.f);
          ((f16*)outp)[idx] = (f16)val;
        } else if constexpr (EPI == 1) {
          val += (float)resid[idx];
          ((f16*)outp)[idx] = (f16)val;
        } else {
          val += (float)resid[idx];
          ((float*)outp)[idx] = val;
        }
      }
    }
  }
}

// ---------------------------------------------------------------------------
// LayerNorm over DIM=1024, one block per row, in-place safe.
// ---------------------------------------------------------------------------
__global__ __launch_bounds__(256) void ln_k(
    const f16* __restrict__ in, f16* __restrict__ out,
    const float* __restrict__ g, const float* __restrict__ b)
{
  __shared__ float red[8];
  const int row = blockIdx.x;
  const int tid = threadIdx.x;
  const int c = tid * 4;
  const f16x4 v4 = *(const f16x4*)(in + (size_t)row * DIM + c);
  const float v0 = v4[0], v1 = v4[1], v2 = v4[2], v3 = v4[3];
  float s  = v0 + v1 + v2 + v3;
  float s2 = v0 * v0 + v1 * v1 + v2 * v2 + v3 * v3;
  #pragma unroll
  for (int off = 32; off; off >>= 1) {
    s  += __shfl_xor(s,  off);
    s2 += __shfl_xor(s2, off);
  }
  if ((tid & 63) == 0) { red[(tid >> 6) * 2] = s; red[(tid >> 6) * 2 + 1] = s2; }
  __syncthreads();
  s  = red[0] + red[2] + red[4] + red[6];
  s2 = red[1] + red[3] + red[5] + red[7];
  const float mu  = s * (1.f / DIM);
  const float var = fmaxf(s2 * (1.f / DIM) - mu * mu, 0.f);
  const float rs  = rsqrtf(var + EPS);
  const float4 gv = *(const float4*)(g + c);
  const float4 bv = *(const float4*)(b + c);
  f16x4 o4;
  o4[0] = (f16)((v0 - mu) * rs * gv.x + bv.x);
  o4[1] = (f16)((v1 - mu) * rs * gv.y + bv.y);
  o4[2] = (f16)((v2 - mu) * rs * gv.z + bv.z);
  o4[3] = (f16)((v3 - mu) * rs * gv.w + bv.w);
  *(f16x4*)(out + (size_t)row * DIM + c) = o4;
}

// ---------------------------------------------------------------------------
extern "C" void kernel_launch(void* const* d_in, const int* in_sizes, int n_in,
                              void* d_out, int out_size, void* d_ws, size_t ws_size,
                              hipStream_t stream)
{
  (void)in_sizes; (void)n_in; (void)out_size; (void)ws_size;
  const float* x     = (const float*)d_in[0];
  const int*   q     = (const int*)d_in[1];
  const float* norm  = (const float*)d_in[2];
  const float* bias  = (const float*)d_in[3];
  const float* la    = (const float*)d_in[4];
  const float* lb    = (const float*)d_in[5];
  const float* lg    = (const float*)d_in[6];
  const float* lbeta = (const float*)d_in[7];

  char* ws = (char*)d_ws;
  f16* W    = (f16*)ws;                                   // 36 MB
  f16* buf1 = (f16*)(ws + (size_t)NLIN * DIM * DIM * 2);  // 32 MB
  f16* buf2 = buf1 + (size_t)TOK * DIM;                   // 32 MB
  f16* buf0 = (f16*)d_out;  // scratch inside the 64MB output; dead at final GEMM
  f16* bufs[3] = {buf0, buf1, buf2};

  prep_w2<<<NLIN * 32, 256, 0, stream>>>(q, norm, la, lb, W);
  cvt_x<<<TOK * DIM / 1024, 256, 0, stream>>>(x, buf0);

  int h = 0;
  for (int blk = 0; blk < 6; ++blk) {
    const int a = (h == 0) ? 1 : 0;
    const int p = 3 - h - a;
    const int i0 = blk * 3;
    const size_t wsz = (size_t)DIM * DIM;
    gemm6<0><<<1024, 256, 0, stream>>>(bufs[h], W + (i0 + 0) * wsz,
                                       bias + (i0 + 0) * DIM, nullptr, bufs[a]);
    gemm6<0><<<1024, 256, 0, stream>>>(bufs[a], W + (i0 + 1) * wsz,
                                       bias + (i0 + 1) * DIM, nullptr, bufs[p]);
    if (blk < 5) {
      gemm6<1><<<1024, 256, 0, stream>>>(bufs[p], W + (i0 + 2) * wsz,
                                         bias + (i0 + 2) * DIM, bufs[h], bufs[a]);
      ln_k<<<TOK, 256, 0, stream>>>(bufs[a], bufs[a], lg + blk * DIM, lbeta + blk * DIM);
      h = a;
    } else {
      gemm6<2><<<1024, 256, 0, stream>>>(bufs[p], W + (i0 + 2) * wsz,
                                         bias + (i0 + 2) * DIM, bufs[h], d_out);
    }
  }
}